// Round 1
// baseline (80.775 us; speedup 1.0000x reference)
//
#include <hip/hip_runtime.h>
#include <hip/hip_bf16.h>
#include <stdint.h>

#define B_ 16
#define C_ 128
#define L_ 2048
#define LOG2E 1.4426950408889634f

typedef __attribute__((ext_vector_type(8))) short bf16x8;
typedef __attribute__((ext_vector_type(4))) float f32x4;

typedef __attribute__((address_space(3))) unsigned int lds_u32_t;
typedef const __attribute__((address_space(1))) unsigned int gbl_u32_t;

__device__ __forceinline__ void gload_lds16(const void* g, void* l) {
  // linear wave-uniform LDS dest (base + lane*16), per-lane global src
  __builtin_amdgcn_global_load_lds((gbl_u32_t*)g,
                                   (lds_u32_t*)(unsigned long long)l, 16, 0, 0);
}

__device__ __forceinline__ unsigned short f2bf(float x) {  // RNE f32->bf16
  union { float f; unsigned u; } v; v.f = x;
  unsigned u = v.u;
  u += 0x7fffu + ((u >> 16) & 1u);
  return (unsigned short)(u >> 16);
}

__device__ __forceinline__ unsigned pk2(float a, float b) {
  return (unsigned)f2bf(a) | ((unsigned)f2bf(b) << 16);
}

// ---------------------------------------------------------------------------
// Projection: Q[b,l,o] = sum_c x[b,c,l]*W1[o,c] + b1[o]   (bf16 out, [B][L][C])
//             K same with W2/b2; V stored transposed Vt[b,o,l] ([B][C][L])
// ---------------------------------------------------------------------------
__global__ __launch_bounds__(256, 2) void proj_kernel(
    const float* __restrict__ x,
    const float* __restrict__ W1, const float* __restrict__ b1,
    const float* __restrict__ W2, const float* __restrict__ b2,
    const float* __restrict__ W3, const float* __restrict__ b3,
    unsigned short* __restrict__ Qo, unsigned short* __restrict__ Ko,
    unsigned short* __restrict__ Vt)
{
  __shared__ unsigned short Xt[64][136];   // [l_local][c], pad 136 breaks conflicts
  __shared__ unsigned short Wl[128][136];  // [o][c]

  const int b  = blockIdx.x & 15;
  const int lt = blockIdx.x >> 4;          // 0..31
  const int l0 = lt * 64;
  const int tid = threadIdx.x;
  const int w = tid >> 6, lane = tid & 63, li = lane & 15, lg = lane >> 4;

  // stage X tile: x[b][c][l0..l0+63] -> Xt[l][c] (bf16)
  for (int it = 0; it < 8; ++it) {
    int idx = tid + it * 256;              // 0..2047
    int c = idx >> 4, f4 = idx & 15;
    const float4 vv = *(const float4*)(x + (size_t)(b * C_ + c) * L_ + l0 + f4 * 4);
    Xt[f4 * 4 + 0][c] = f2bf(vv.x);
    Xt[f4 * 4 + 1][c] = f2bf(vv.y);
    Xt[f4 * 4 + 2][c] = f2bf(vv.z);
    Xt[f4 * 4 + 3][c] = f2bf(vv.w);
  }

  auto stageW = [&](const float* W) {
    for (int it = 0; it < 16; ++it) {
      int idx = tid + it * 256;            // 0..4095
      int o = idx >> 5, f4 = idx & 31;
      const float4 vv = *(const float4*)(W + (size_t)o * C_ + f4 * 4);
      unsigned short* p = &Wl[o][f4 * 4];
      p[0] = f2bf(vv.x); p[1] = f2bf(vv.y); p[2] = f2bf(vv.z); p[3] = f2bf(vv.w);
    }
  };

  // mode 0: write [B][L][C] (Q/K). mode 1: write transposed [B][C][L] (Vt).
  auto computePhase = [&](const float* bias, unsigned short* Out, int mode) {
    f32x4 acc[8];
#pragma unroll
    for (int ni = 0; ni < 8; ++ni) acc[ni] = (f32x4){0.f, 0.f, 0.f, 0.f};
    bf16x8 af[4];
#pragma unroll
    for (int kk = 0; kk < 4; ++kk)
      af[kk] = *(const bf16x8*)&Xt[w * 16 + li][lg * 8 + kk * 32];
#pragma unroll
    for (int kk = 0; kk < 4; ++kk) {
#pragma unroll
      for (int ni = 0; ni < 8; ++ni) {
        bf16x8 bf = *(const bf16x8*)&Wl[ni * 16 + li][lg * 8 + kk * 32];
        acc[ni] = __builtin_amdgcn_mfma_f32_16x16x32_bf16(af[kk], bf, acc[ni], 0, 0, 0);
      }
    }
    if (mode == 0) {
#pragma unroll
      for (int ni = 0; ni < 8; ++ni) {
        float bv = bias[ni * 16 + li];
#pragma unroll
        for (int r = 0; r < 4; ++r) {
          int lrow = l0 + w * 16 + lg * 4 + r;
          Out[(size_t)(b * L_ + lrow) * C_ + ni * 16 + li] = f2bf(acc[ni][r] + bv);
        }
      }
    } else {
#pragma unroll
      for (int ni = 0; ni < 8; ++ni) {
        float bv = bias[ni * 16 + li];
        int o = ni * 16 + li;
        unsigned long long pw =
            (unsigned long long)pk2(acc[ni][0] + bv, acc[ni][1] + bv) |
            ((unsigned long long)pk2(acc[ni][2] + bv, acc[ni][3] + bv) << 32);
        *(unsigned long long*)(Out + (size_t)(b * C_ + o) * L_ + l0 + w * 16 + lg * 4) = pw;
      }
    }
  };

  stageW(W1);
  __syncthreads();
  computePhase(b1, Qo, 0);
  __syncthreads();
  stageW(W2);
  __syncthreads();
  computePhase(b2, Ko, 0);
  __syncthreads();
  stageW(W3);
  __syncthreads();
  computePhase(b3, Vt, 1);
}

// ---------------------------------------------------------------------------
// Flash attention: per block = (batch, 128 q-rows), 8 waves x 16 rows.
// S^T = mfma(K, Q); online softmax in-lane; P via per-wave LDS; O^T = mfma(Vt, P^T).
// K/V staged with global_load_lds (linear dest, pre-swizzled src, XOR-swz reads).
// ---------------------------------------------------------------------------
__global__ __launch_bounds__(512, 2) void attn_kernel(
    const unsigned short* __restrict__ Q,
    const unsigned short* __restrict__ K,
    const unsigned short* __restrict__ Vt,
    float* __restrict__ out)
{
  __shared__ unsigned short kbuf[2][64 * C_];   // [j][c], rows 256B, swizzled
  __shared__ unsigned short vbuf[2][C_ * 64];   // [c][j], rows 128B, swizzled
  __shared__ unsigned short pbuf[8][16 * 64];   // per-wave P, rows 128B, swizzled

  const int b  = blockIdx.x & 15;               // same-batch blocks -> same XCD
  const int qt = blockIdx.x >> 4;
  const int tid = threadIdx.x;
  const int w = tid >> 6, lane = tid & 63, li = lane & 15, lg = lane >> 4;
  const int qrow0 = qt * 128 + w * 16;
  const size_t bLC = (size_t)b * L_ * C_;

  // Q fragments (B operand of S^T): lane holds Q[qrow0+li][lg*8 + kk*32 ..+7]
  bf16x8 qf[4];
  {
    const unsigned short* qp = Q + bLC + (size_t)(qrow0 + li) * C_ + lg * 8;
#pragma unroll
    for (int kk = 0; kk < 4; ++kk) qf[kk] = *(const bf16x8*)(qp + kk * 32);
  }

  f32x4 oacc[8];
#pragma unroll
  for (int i = 0; i < 8; ++i) oacc[i] = (f32x4){0.f, 0.f, 0.f, 0.f};
  float mrun = -1e30f, lrun = 0.f;

  const char* kgb = (const char*)(K + bLC);
  const char* vgb = (const char*)(Vt + bLC);

  auto stage = [&](int sel, int t) {
    const char* kt  = kgb + (size_t)t * (64 * 256);   // K tile base (16KB)
    const char* vt0 = vgb + (size_t)t * 128;          // V tile col-byte offset
    int dbase = w * 2048;                             // wave-uniform chunk
#pragma unroll
    for (int i2 = 0; i2 < 2; ++i2) {
      int db = dbase + i2 * 1024;
      int d  = db + lane * 16;
      int row = d >> 8, cb = d & 255;                 // K: 256B rows
      gload_lds16(kt + row * 256 + (cb ^ ((row & 7) << 4)), (char*)kbuf[sel] + db);
      int rowv = d >> 7, cbv = d & 127;               // V: 128B rows
      gload_lds16(vt0 + (size_t)rowv * (L_ * 2) + (cbv ^ ((rowv & 7) << 4)),
                  (char*)vbuf[sel] + db);
    }
  };

  stage(0, 0);
  __syncthreads();

  int cur = 0;
  for (int t = 0; t < 32; ++t) {
    if (t + 1 < 32) stage(cur ^ 1, t + 1);

    // ---- QK^T: S^T[j, i] for j in 4 m-tiles
    const char* kb = (const char*)kbuf[cur];
    bf16x8 kf[4][4];
#pragma unroll
    for (int mt = 0; mt < 4; ++mt) {
      int row = mt * 16 + li;
      int rb = row << 8, swz = (row & 7) << 4;
#pragma unroll
      for (int kk = 0; kk < 4; ++kk)
        kf[mt][kk] = *(const bf16x8*)(kb + rb + ((lg * 16 + kk * 64) ^ swz));
    }
    f32x4 s[4];
#pragma unroll
    for (int mt = 0; mt < 4; ++mt) {
      s[mt] = (f32x4){0.f, 0.f, 0.f, 0.f};
#pragma unroll
      for (int kk = 0; kk < 4; ++kk)
        s[mt] = __builtin_amdgcn_mfma_f32_16x16x32_bf16(kf[mt][kk], qf[kk], s[mt], 0, 0, 0);
    }

    // ---- online softmax (lane owns query li; j = mt*16 + lg*4 + r)
    float pmax = -1e30f;
#pragma unroll
    for (int mt = 0; mt < 4; ++mt)
#pragma unroll
      for (int r = 0; r < 4; ++r) pmax = fmaxf(pmax, s[mt][r]);
    pmax = fmaxf(pmax, __shfl_xor(pmax, 16));
    pmax = fmaxf(pmax, __shfl_xor(pmax, 32));
    float mnew  = fmaxf(mrun, pmax);
    float alpha = exp2f((mrun - mnew) * LOG2E);
    float psum = 0.f;
#pragma unroll
    for (int mt = 0; mt < 4; ++mt) {
      float p0 = exp2f((s[mt][0] - mnew) * LOG2E);
      float p1 = exp2f((s[mt][1] - mnew) * LOG2E);
      float p2 = exp2f((s[mt][2] - mnew) * LOG2E);
      float p3 = exp2f((s[mt][3] - mnew) * LOG2E);
      psum += (p0 + p1) + (p2 + p3);
      unsigned long long pw = (unsigned long long)pk2(p0, p1) |
                              ((unsigned long long)pk2(p2, p3) << 32);
      int cb = mt * 32 + lg * 8;
      *(unsigned long long*)((char*)pbuf[w] + li * 128 + (cb ^ ((li & 7) << 4))) = pw;
    }
    psum += __shfl_xor(psum, 16);
    psum += __shfl_xor(psum, 32);
    lrun = lrun * alpha + psum;
#pragma unroll
    for (int ct = 0; ct < 8; ++ct) oacc[ct] = oacc[ct] * alpha;
    mrun = mnew;

    // ---- PV: O^T[c, i] += Vt_tile * P^T (per-wave LDS round trip for P)
    bf16x8 pf[2];
#pragma unroll
    for (int kk2 = 0; kk2 < 2; ++kk2)
      pf[kk2] = *(const bf16x8*)((const char*)pbuf[w] + li * 128 +
                                 ((lg * 16 + kk2 * 64) ^ ((li & 7) << 4)));
    const char* vb = (const char*)vbuf[cur];
#pragma unroll
    for (int ct = 0; ct < 8; ++ct) {
      int row = ct * 16 + li;
      int rb = row << 7, swz = (row & 7) << 4;
#pragma unroll
      for (int kk2 = 0; kk2 < 2; ++kk2) {
        bf16x8 vf = *(const bf16x8*)(vb + rb + ((lg * 16 + kk2 * 64) ^ swz));
        oacc[ct] = __builtin_amdgcn_mfma_f32_16x16x32_bf16(vf, pf[kk2], oacc[ct], 0, 0, 0);
      }
    }
    __syncthreads();
    cur ^= 1;
  }

  // ---- epilogue: out[b][c][l] = O^T[c, i] / l_i
  float inv = 1.0f / lrun;
  float* ob = out + (size_t)b * C_ * L_;
  int lcol = qt * 128 + w * 16 + li;
#pragma unroll
  for (int ct = 0; ct < 8; ++ct) {
    int c = ct * 16 + lg * 4;
#pragma unroll
    for (int r = 0; r < 4; ++r)
      ob[(size_t)(c + r) * L_ + lcol] = oacc[ct][r] * inv;
  }
}

extern "C" void kernel_launch(void* const* d_in, const int* in_sizes, int n_in,
                              void* d_out, int out_size, void* d_ws, size_t ws_size,
                              hipStream_t stream) {
  (void)in_sizes; (void)n_in; (void)out_size; (void)ws_size;
  const float* x  = (const float*)d_in[0];
  const float* W1 = (const float*)d_in[1];
  const float* b1 = (const float*)d_in[2];
  const float* W2 = (const float*)d_in[3];
  const float* b2 = (const float*)d_in[4];
  const float* W3 = (const float*)d_in[5];
  const float* b3 = (const float*)d_in[6];

  unsigned short* Q  = (unsigned short*)d_ws;              // [B][L][C] bf16
  unsigned short* K  = Q + (size_t)B_ * L_ * C_;           // [B][L][C] bf16
  unsigned short* Vt = K + (size_t)B_ * L_ * C_;           // [B][C][L] bf16

  proj_kernel<<<512, 256, 0, stream>>>(x, W1, b1, W2, b2, W3, b3, Q, K, Vt);
  attn_kernel<<<256, 512, 0, stream>>>(Q, K, Vt, (float*)d_out);
}